// Round 1
// baseline (232.096 us; speedup 1.0000x reference)
//
#include <hip/hip_runtime.h>

#define NIN 64
#define NOUT 32
#define TBITS 21                 // 128^3 stride-2 lattice
#define TSIZE (1 << TBITS)

typedef __attribute__((ext_vector_type(8))) short short8;
typedef __attribute__((ext_vector_type(4))) float float4v;
typedef __attribute__((ext_vector_type(4))) unsigned short ushort4v;

__device__ __forceinline__ unsigned short bf16rne(float x) {
    unsigned u = __float_as_uint(x);
    u += 0x7fffu + ((u >> 16) & 1u);
    return (unsigned short)(u >> 16);
}

// ws (ints): [0,2M) table | [2M, A) sorted(-1 padded, A aligned) |
//            A: count[8] | pbase[9] at A+8 | cursor[8] at A+20 |
//            wt bf16 [27][32][64] at int offset A+32 |
//            fb bf16 [Np][64] after wt (16B aligned), if ws_size permits
__global__ void init_all(int4* __restrict__ ws4, int n4, int* __restrict__ count) {
    int i = blockIdx.x * blockDim.x + threadIdx.x;
    if (i < n4) ws4[i] = make_int4(-1, -1, -1, -1);
    if (i < 8) count[i] = 0;
}

__global__ void build_table(const int* __restrict__ coords, int np,
                            int* __restrict__ table) {
    int i = blockIdx.x * blockDim.x + threadIdx.x;
    if (i >= np) return;
    int x = coords[i * 4 + 1];
    int y = coords[i * 4 + 2];
    int z = coords[i * 4 + 3];
    table[(x >> 1) | ((y >> 1) << 7) | ((z >> 1) << 14)] = i;
}

__global__ void count_classes(const int* __restrict__ guide, int ng,
                              int* __restrict__ count) {
    __shared__ int lc[8];
    if (threadIdx.x < 8) lc[threadIdx.x] = 0;
    __syncthreads();
    int g = blockIdx.x * blockDim.x + threadIdx.x;
    if (g < ng) {
        int4 q = ((const int4*)guide)[g];
        int c = (q.y & 1) | ((q.z & 1) << 1) | ((q.w & 1) << 2);
        atomicAdd(&lc[c], 1);
    }
    __syncthreads();
    if (threadIdx.x < 8 && lc[threadIdx.x]) atomicAdd(&count[threadIdx.x], lc[threadIdx.x]);
}

// 16-aligned padded exclusive scan; seed cursor
__global__ void scan8(const int* __restrict__ count, int* __restrict__ pbase,
                      int* __restrict__ cursor) {
    if (threadIdx.x == 0 && blockIdx.x == 0) {
        int s = 0;
        for (int c = 0; c < 8; ++c) {
            pbase[c] = s; cursor[c] = s;
            s += (count[c] + 15) & ~15;
        }
        pbase[8] = s;
    }
}

__global__ void scatter_guides(const int* __restrict__ guide, int ng,
                               int* __restrict__ cursor, int* __restrict__ sorted) {
    __shared__ int lc[8];
    __shared__ int lbase[8];
    int t = threadIdx.x;
    if (t < 8) lc[t] = 0;
    __syncthreads();
    int g = blockIdx.x * blockDim.x + t;
    int c = 0, lrank = 0;
    bool ok = g < ng;
    if (ok) {
        int4 q = ((const int4*)guide)[g];
        c = (q.y & 1) | ((q.z & 1) << 1) | ((q.w & 1) << 2);
        lrank = atomicAdd(&lc[c], 1);
    }
    __syncthreads();
    if (t < 8) lbase[t] = lc[t] ? atomicAdd(&cursor[t], lc[t]) : 0;
    __syncthreads();
    if (ok) sorted[lbase[c] + lrank] = g;
}

// fp32 [27][64][32] -> bf16 transposed [27][32][64]
__global__ void wcvt(const float* __restrict__ w, unsigned short* __restrict__ wt) {
    int i = blockIdx.x * blockDim.x + threadIdx.x;
    if (i < 27 * 64 * 32) {
        int oi = i >> 11;
        int k  = (i >> 5) & 63;
        int ch = i & 31;
        wt[oi * 2048 + ch * 64 + k] = bf16rne(w[i]);
    }
}

// fp32 feats -> bf16 mirror (streaming, 4 elems/thread)
__global__ void fcvt(const float* __restrict__ f, unsigned short* __restrict__ fb,
                     int n4) {
    int i = blockIdx.x * blockDim.x + threadIdx.x;
    if (i < n4) {
        float4 v = ((const float4*)f)[i];
        ushort4v o;
        o.x = bf16rne(v.x); o.y = bf16rne(v.y);
        o.z = bf16rne(v.z); o.w = bf16rne(v.w);
        ((ushort4v*)fb)[i] = o;
    }
}

// ---- main: one wave per tile of 16 same-parity-class guides.
// Probe: lane=(slot 0..3, m 0..15), 2 rounds -> idx0/idx1 + ballots.
// GEMM: per admissible slot, A[16x64] gathered bf16 (miss rows skip load),
// B from global bf16 wt, 4x mfma_f32_16x16x32_bf16 into two f32x4 accs.
// C layout: col(n)=lane&15, row(m)=quad*4+reg. ----
template<int USEFB>
__launch_bounds__(256, 4)
__global__ void gen_conv(const float* __restrict__ feats,        // [Np,64] fp32
                         const unsigned short* __restrict__ fb,  // [Np,64] bf16 (if USEFB)
                         const float* __restrict__ bias,         // [32]
                         const int* __restrict__ guide,          // [Ng,4]
                         const int* __restrict__ table,          // [2^21]
                         const int* __restrict__ sorted,         // padded
                         const int* __restrict__ pbase,          // [9]
                         const unsigned short* __restrict__ wt,  // [27][32][64] bf16
                         float* __restrict__ out, int ng) {
    int tile = blockIdx.x * 4 + (threadIdx.x >> 6);
    int lane = threadIdx.x & 63;
    int m    = lane & 15;          // guide-row in tile / B n-col
    int quad = lane >> 4;          // k-octet / probe slot base

    int total = pbase[8];
    int t16 = tile * 16;
    if (t16 >= total) return;

    // class of this tile (pbase monotone)
    int c = 0;
    #pragma unroll
    for (int j = 1; j < 8; ++j) c += (t16 >= pbase[j]) ? 1 : 0;
    c = __builtin_amdgcn_readfirstlane(c);
    int ex = c & 1, ey = (c >> 1) & 1, ez = (c >> 2) & 1;

    int id = sorted[t16 + m];
    int4 q = ((const int4*)guide)[id < 0 ? 0 : id];
    int qx = q.y, qy = q.z, qz = q.w;

    // probe rounds: sub = quad (round0), quad+4 (round1)
    int idxr[2];
    #pragma unroll
    for (int r = 0; r < 2; ++r) {
        int sub = quad + r * 4;
        int offx = ex ? ((sub & 1) ? 1 : -1) : 0;
        int offy = ey ? ((sub & 2) ? 1 : -1) : 0;
        int offz = ez ? ((sub & 4) ? 1 : -1) : 0;
        int px = qx - offx, py = qy - offy, pz = qz - offz;
        bool valid = (id >= 0) & ((sub & ~c & 7) == 0) &
                     ((unsigned)px < 256u) & ((unsigned)py < 256u) & ((unsigned)pz < 256u);
        int lin = (px >> 1) | ((py >> 1) << 7) | ((pz >> 1) << 14);
        int v = table[valid ? lin : 0];
        idxr[r] = valid ? v : -1;
    }

    unsigned long long bal0 = __ballot(idxr[0] >= 0);
    unsigned long long bal1 = __ballot(idxr[1] >= 0);
    unsigned long long eb = bal0 | bal1;
    unsigned e16 = (unsigned)((eb | (eb >> 16) | (eb >> 32) | (eb >> 48)) & 0xffffull);

    float4v acc0 = {0.f, 0.f, 0.f, 0.f};
    float4v acc1 = {0.f, 0.f, 0.f, 0.f};

    #pragma unroll
    for (int sub = 0; sub < 8; ++sub) {
        if (sub & ~c & 7) continue;    // inadmissible for this class (uniform)
        unsigned long long bal = (sub < 4) ? bal0 : bal1;
        unsigned rowm = (unsigned)((bal >> ((sub & 3) * 16)) & 0xffffull);
        if (rowm == 0) continue;

        int srcl = (sub & 3) * 16 + m;
        int hidx = __shfl((sub < 4) ? idxr[0] : idxr[1], srcl, 64);

        // A fragments: row m, k = quad*8+j (a0: k<32, a1: k>=32)
        short8 a0 = {0,0,0,0,0,0,0,0};
        short8 a1 = {0,0,0,0,0,0,0,0};
        if (hidx >= 0) {
            if constexpr (USEFB) {
                const unsigned short* fp = fb + (size_t)hidx * NIN + quad * 8;
                a0 = *(const short8*)fp;
                a1 = *(const short8*)(fp + 32);
            } else {
                const float4* fp = (const float4*)(feats + (size_t)hidx * NIN + quad * 8);
                float4 fA = fp[0], fB = fp[1];
                const float4* fp2 = (const float4*)(feats + (size_t)hidx * NIN + 32 + quad * 8);
                float4 fC = fp2[0], fD = fp2[1];
                a0[0] = (short)bf16rne(fA.x); a0[1] = (short)bf16rne(fA.y);
                a0[2] = (short)bf16rne(fA.z); a0[3] = (short)bf16rne(fA.w);
                a0[4] = (short)bf16rne(fB.x); a0[5] = (short)bf16rne(fB.y);
                a0[6] = (short)bf16rne(fB.z); a0[7] = (short)bf16rne(fB.w);
                a1[0] = (short)bf16rne(fC.x); a1[1] = (short)bf16rne(fC.y);
                a1[2] = (short)bf16rne(fC.z); a1[3] = (short)bf16rne(fC.w);
                a1[4] = (short)bf16rne(fD.x); a1[5] = (short)bf16rne(fD.y);
                a1[6] = (short)bf16rne(fD.z); a1[7] = (short)bf16rne(fD.w);
            }
        }

        int offx = ex ? ((sub & 1) ? 1 : -1) : 0;
        int offy = ey ? ((sub & 2) ? 1 : -1) : 0;
        int offz = ez ? ((sub & 4) ? 1 : -1) : 0;
        int oi = (offx + 1) * 9 + (offy + 1) * 3 + (offz + 1);

        // B fragments: lane holds B[k=quad*8+j][n=m]; wt[oi][ch][k]
        const unsigned short* wb = wt + oi * 2048 + m * 64 + quad * 8;
        short8 b00 = *(const short8*)(wb);               // k<32,  ch m
        short8 b01 = *(const short8*)(wb + 1024);        // k<32,  ch 16+m
        short8 b10 = *(const short8*)(wb + 32);          // k>=32, ch m
        short8 b11 = *(const short8*)(wb + 1024 + 32);   // k>=32, ch 16+m

        acc0 = __builtin_amdgcn_mfma_f32_16x16x32_bf16(a0, b00, acc0, 0, 0, 0);
        acc0 = __builtin_amdgcn_mfma_f32_16x16x32_bf16(a1, b10, acc0, 0, 0, 0);
        acc1 = __builtin_amdgcn_mfma_f32_16x16x32_bf16(a0, b01, acc1, 0, 0, 0);
        acc1 = __builtin_amdgcn_mfma_f32_16x16x32_bf16(a1, b11, acc1, 0, 0, 0);
    }

    // store: lane's col n=m; rows mr=quad*4+r
    float bv0 = bias[m], bv1 = bias[16 + m];
    #pragma unroll
    for (int r = 0; r < 4; ++r) {
        int mr = quad * 4 + r;
        int idr = __shfl(id, mr, 64);      // lanes 0..15 hold the 16 ids
        if (idr >= 0) {
            bool exr = (e16 >> mr) & 1;
            float v0 = exr ? (acc0[r] + bv0) : 0.f;
            float v1 = exr ? (acc1[r] + bv1) : 0.f;
            out[(size_t)idr * NOUT + m]      = v0;
            out[(size_t)idr * NOUT + 16 + m] = v1;
        }
    }
}

extern "C" void kernel_launch(void* const* d_in, const int* in_sizes, int n_in,
                              void* d_out, int out_size, void* d_ws, size_t ws_size,
                              hipStream_t stream) {
    const float* feats   = (const float*)d_in[0];
    const float* weights = (const float*)d_in[1];
    const float* bias    = (const float*)d_in[2];
    const int*   coords  = (const int*)d_in[3];
    const int*   guide   = (const int*)d_in[4];
    float* out = (float*)d_out;

    int np = in_sizes[3] / 4;
    int ng = in_sizes[4] / 4;

    int* wsI = (int*)d_ws;
    int* table  = wsI;                       // 2^21
    int* sorted = wsI + TSIZE;               // ng+128, -1 padded
    int A = TSIZE + ((ng + 128 + 3) & ~3);   // int4-aligned
    int* count  = wsI + A;                   // 8
    int* pbase  = wsI + A + 8;               // 9
    int* cursor = wsI + A + 20;              // 8
    unsigned short* wt = (unsigned short*)(wsI + A + 32);   // 27*32*64 bf16
    // bf16 feats mirror after wt (wt = 27648 ints), 16B aligned
    size_t fbOffI = (size_t)A + 32 + 27 * 2048 / 2;          // ints
    unsigned short* fb = (unsigned short*)(wsI + fbOffI);
    size_t need = fbOffI * 4 + (size_t)np * NIN * 2;
    int usefb = (ws_size >= need) ? 1 : 0;

    int n4 = A / 4;
    hipLaunchKernelGGL(init_all, dim3((n4 + 255) / 256), dim3(256), 0, stream,
                       (int4*)wsI, n4, count);
    hipLaunchKernelGGL(build_table, dim3((np + 255) / 256), dim3(256), 0, stream,
                       coords, np, table);
    hipLaunchKernelGGL(count_classes, dim3((ng + 255) / 256), dim3(256), 0, stream,
                       guide, ng, count);
    hipLaunchKernelGGL(scan8, dim3(1), dim3(64), 0, stream, count, pbase, cursor);
    hipLaunchKernelGGL(scatter_guides, dim3((ng + 255) / 256), dim3(256), 0, stream,
                       guide, ng, cursor, sorted);
    hipLaunchKernelGGL(wcvt, dim3((27 * 64 * 32 + 255) / 256), dim3(256), 0, stream,
                       weights, wt);
    if (usefb) {
        int fn4 = np * NIN / 4;
        hipLaunchKernelGGL(fcvt, dim3((fn4 + 255) / 256), dim3(256), 0, stream,
                           feats, fb, fn4);
    }

    int maxtiles = (ng + 8 * 15 + 15) / 16;
    int blocks = (maxtiles + 3) / 4;         // 4 waves (tiles) per block
    if (usefb) {
        hipLaunchKernelGGL((gen_conv<1>), dim3(blocks), dim3(256), 0, stream,
                           feats, fb, bias, guide, table, sorted, pbase, wt, out, ng);
    } else {
        hipLaunchKernelGGL((gen_conv<0>), dim3(blocks), dim3(256), 0, stream,
                           feats, fb, bias, guide, table, sorted, pbase, wt, out, ng);
    }
}